// Round 13
// baseline (88.380 us; speedup 1.0000x reference)
//
#include <hip/hip_runtime.h>
#include <hip/hip_bf16.h>

#define BATCH 131072
#define PITCH_H 72   // half-tile row: 64 + 8 pad bf16 (144 B = 9x16B; rows stay 16B-aligned)

typedef __bf16 bf16x4 __attribute__((ext_vector_type(4)));
typedef __bf16 bf16x8 __attribute__((ext_vector_type(8)));
typedef float floatx4 __attribute__((ext_vector_type(4)));

#define GLOBAL_AS __attribute__((address_space(1)))
#define LDS_AS __attribute__((address_space(3)))

// Weights carry the tanh's factor 2 (exact in FP: bf16(2w) == 2*bf16(w)), so
// the GEMM output y equals 2*preact bit-exactly and tanh needs no input mul:
// tanh = 1 - 2/(exp(y)+1); exp overflow -> inf -> rcp -> 0 -> +1 (correct limit)
__device__ __forceinline__ float fast_tanh2(float y) {
    float e = __expf(y);
    return 1.0f - 2.0f * __builtin_amdgcn_rcpf(e + 1.0f);
}

// d_ws element layout (bf16):
// [0,16384)       W2s : frag-swizzled 2*W2              (GEMM1)
// [16384,32768)   GTs : frag-swizzled G^T, G=W2*C^T     (GEMM2, unscaled)
// [32768,36864)   W1s : frag-swizzled 2*W1, K pad to 32; rows k=9,10 = 2*b1 hi/lo (GEMM0)
// [36864,38912)   W3s : frag-swizzled W3, N pad to 16   (GEMM3, unscaled)
// swizzle: idx = ((kb*N + n)*4 + q)*8 + j  <->  M[k = kb*32 + q*8 + j][n]
// Operand-swap symmetry: A-frag of M^T == B-frag of M for mfma_16x16x32, so
// these fragments serve the transposed GEMMs with no prep change.

__global__ void prep_kernel(const float* __restrict__ W1,
                            const float* __restrict__ W2,
                            const float* __restrict__ W3,
                            const float* __restrict__ b1,
                            __bf16* __restrict__ ws) {
    int idx = blockIdx.x * 256 + threadIdx.x;
    if (idx < 16384) {
        int j = idx & 7, q = (idx >> 3) & 3, n = (idx >> 5) & 127, kb = idx >> 12;
        int k = kb * 32 + q * 8 + j;
        ws[idx] = (__bf16)(2.0f * W2[k * 128 + n]);          // x2 fold (exact)
        float c = 0.0f;
        #pragma unroll
        for (int d = 0; d < 8; ++d) c += W3[k * 8 + d] * W1[d * 128 + n];
        ws[16384 + idx] = (__bf16)(W2[n * 128 + k] * c);     // GT unscaled
    } else if (idx < 20480) {
        int t = idx - 16384;
        int j = t & 7, q = (t >> 3) & 3, n = t >> 5;   // kb==0 only
        int k = q * 8 + j;
        __bf16 v = (__bf16)0.0f;
        if (k < 9) v = (__bf16)(2.0f * W1[k * 128 + n]);     // x2 fold (exact)
        else if (k == 9) v = (__bf16)(2.0f * b1[n]);         // 2*bias hi (x[9]=1)
        else if (k == 10) {                                  // 2*bias lo (x[10]=1)
            float b2x = 2.0f * b1[n];
            float hi = (float)(__bf16)b2x;
            v = (__bf16)(b2x - hi);
        }
        ws[32768 + t] = v;
    } else if (idx < 22528) {
        int t = idx - 20480;
        int j = t & 7, q = (t >> 3) & 3, n = (t >> 5) & 15, kb = t >> 9;
        int k = kb * 32 + q * 8 + j;
        ws[36864 + t] = (n < 8) ? (__bf16)W3[k * 8 + n] : (__bf16)0.0f;
    }
}

// Structure rationale (rounds 0-12 evidence):
//  - R12 (DMA staging, 512x2it single residency round): best, cnf ~28.5us.
//    Inventory: ~256 tanh/wave-iter at 4 VALU + 2 trans each (~4100cy)
//    dominates -> tanh chain is the issue-load bottleneck.
//  - THIS ROUND: fold tanh's factor 2 into W1s/b1/W2s/b2 at prep. x2 is
//    EXACT in FP, so results are bit-identical (absmax must stay 0.015625)
//    while removing one v_mul per activation (-256 VALU/wave-iter, ~12%).
//  - LDS = 32(W2)+32(GT)+9(tiles)+0.5(b2) = 73.5 KB -> 2 blocks/CU.
//  - launch_bounds(256,2) ONLY: budget-256 is the proven spill-free regime
//    (R0 128, R3 72, R7 128 VGPR). min-waves>=4 attrs -> 64-VGPR acc-split
//    + ~200 MB scratch spill (R1/R2). Watch: FETCH must stay ~5-8 MB.
__global__ __launch_bounds__(256, 2) void cnf_main(
        const float* __restrict__ z, const float* __restrict__ t_ptr,
        const float* __restrict__ b1g, const float* __restrict__ b2g,
        const float* __restrict__ b3g, const __bf16* __restrict__ ws,
        float* __restrict__ out) {
    __shared__ __bf16 sW2s[16384];                             // 32 KB
    __shared__ __bf16 sGTs[16384];                             // 32 KB
    __shared__ float sb2f[128];                                // 512 B (holds 2*b2)
    __shared__ __align__(16) __bf16 tile[4][16 * PITCH_H];     // 9 KB

    const int tid = threadIdx.x;
    const int lane = tid & 63;
    const int w = tid >> 6;
    const int p = lane & 15;       // sample index (C/D col in all GEMMs)
    const int q = lane >> 4;       // quad (C/D row group)
    const float tval = t_ptr[0];

    // ---- hoisted scalar/frag loads (issue before DMA; GEMM0 needs them) ----
    const bf16x8* W1g = (const bf16x8*)(ws + 32768);
    const bf16x8* W3g = (const bf16x8*)(ws + 36864);
    bf16x8 w1f[8];
    #pragma unroll
    for (int nt = 0; nt < 8; ++nt) w1f[nt] = W1g[(nt * 16 + p) * 4 + q];
    bf16x8 w3f[4];
    #pragma unroll
    for (int kb = 0; kb < 4; ++kb) w3f[kb] = W3g[(kb * 16 + p) * 4 + q];
    floatx4 b3f = {0.f, 0.f, 0.f, 0.f};
    if (q < 2) b3f = *(const floatx4*)(b3g + q * 4);   // dz rows q*4+r (real d<8)
    const float b2v = (tid < 128) ? 2.0f * b2g[tid] : 0.0f;   // x2 fold

    // z for it 0 (q==0 lanes; latency hides under DMA issue + GEMM0 prep)
    float4 zc0a, zc1a, zc0b, zc1b;
    {
        const int sb0 = blockIdx.x * 256 + w * 32;
        if (q == 0) {
            const float4* zp0 = (const float4*)(z + (size_t)(sb0 + p) * 8);
            const float4* zp1 = (const float4*)(z + (size_t)(sb0 + 16 + p) * 8);
            zc0a = zp0[0]; zc1a = zp0[1]; zc0b = zp1[0]; zc1b = zp1[1];
        }
    }

    // ---- async DMA staging of W2 + GT (linear, wave-uniform base + lane*16) ----
    {
        const uint4* srcW2v = (const uint4*)ws;
        const uint4* srcGTv = (const uint4*)(ws + 16384);
        uint4* dstW2v = (uint4*)sW2s;
        uint4* dstGTv = (uint4*)sGTs;
        #pragma unroll
        for (int i = 0; i < 8; ++i) {
            const int idx = tid + i * 256;
            const int wbase = w * 64 + i * 256;   // wave-uniform uint4 index
            __builtin_amdgcn_global_load_lds(
                (const GLOBAL_AS uint4*)(srcW2v + idx),
                (LDS_AS uint4*)(dstW2v + wbase), 16, 0, 0);
            __builtin_amdgcn_global_load_lds(
                (const GLOBAL_AS uint4*)(srcGTv + idx),
                (LDS_AS uint4*)(dstGTv + wbase), 16, 0, 0);
        }
    }

    __bf16* T = tile[w];
    const bf16x8* W2sv = (const bf16x8*)sW2s;
    const bf16x8* GTsv = (const bf16x8*)sGTs;

    float4 zn0a, zn1a, zn0b, zn1b;   // prefetched z for it 1

    #pragma unroll
    for (int it = 0; it < 2; ++it) {
        const int sbase = blockIdx.x * 256 + it * 128 + w * 32;

        // ---- build B-frags of X^T: lane holds x[sample p][k=q*8+j] ----
        bf16x8 ax0, ax1;
        #pragma unroll
        for (int j = 0; j < 8; ++j) { ax0[j] = (__bf16)0.0f; ax1[j] = (__bf16)0.0f; }
        if (q == 0) {
            ax0[0] = (__bf16)zc0a.x; ax0[1] = (__bf16)zc0a.y;
            ax0[2] = (__bf16)zc0a.z; ax0[3] = (__bf16)zc0a.w;
            ax0[4] = (__bf16)zc1a.x; ax0[5] = (__bf16)zc1a.y;
            ax0[6] = (__bf16)zc1a.z; ax0[7] = (__bf16)zc1a.w;
            ax1[0] = (__bf16)zc0b.x; ax1[1] = (__bf16)zc0b.y;
            ax1[2] = (__bf16)zc0b.z; ax1[3] = (__bf16)zc0b.w;
            ax1[4] = (__bf16)zc1b.x; ax1[5] = (__bf16)zc1b.y;
            ax1[6] = (__bf16)zc1b.z; ax1[7] = (__bf16)zc1b.w;
        } else if (q == 1) {
            ax0[0] = (__bf16)tval; ax0[1] = (__bf16)1.0f; ax0[2] = (__bf16)1.0f;
            ax1[0] = (__bf16)tval; ax1[1] = (__bf16)1.0f; ax1[2] = (__bf16)1.0f;
        }

        // ---- GEMM0: 2*h1pre = mfma(2W1^T-frag, X^T-frag); bias via K-slots ----
        float a1c0[32], a1c1[32];
        bf16x8 aha[4], ahb[4];
        #pragma unroll
        for (int h = 0; h < 2; ++h) {
            floatx4 accA[4], accB[4];
            #pragma unroll
            for (int lt = 0; lt < 4; ++lt) {
                const floatx4 zz = {0.f, 0.f, 0.f, 0.f};
                accA[lt] = __builtin_amdgcn_mfma_f32_16x16x32_bf16(w1f[4 * h + lt], ax0, zz, 0, 0, 0);
                accB[lt] = __builtin_amdgcn_mfma_f32_16x16x32_bf16(w1f[4 * h + lt], ax1, zz, 0, 0, 0);
            }
            #pragma unroll
            for (int lt = 0; lt < 4; ++lt) {            // group a epilogue
                bf16x4 v;
                #pragma unroll
                for (int r = 0; r < 4; ++r) {
                    const float h1 = fast_tanh2(accA[lt][r]);
                    a1c0[(4 * h + lt) * 4 + r] = __builtin_fmaf(-h1, h1, 1.0f);
                    v[r] = (__bf16)h1;
                }
                *(bf16x4*)&T[p * PITCH_H + lt * 16 + q * 4] = v;   // contiguous b64
            }
            // wave-private in-order DS: write->read round-trip safe, no barrier
            aha[2 * h]     = *(const bf16x8*)&T[p * PITCH_H + q * 8];
            aha[2 * h + 1] = *(const bf16x8*)&T[p * PITCH_H + 32 + q * 8];
            #pragma unroll
            for (int lt = 0; lt < 4; ++lt) {            // group b epilogue (tile reused)
                bf16x4 v;
                #pragma unroll
                for (int r = 0; r < 4; ++r) {
                    const float h1 = fast_tanh2(accB[lt][r]);
                    a1c1[(4 * h + lt) * 4 + r] = __builtin_fmaf(-h1, h1, 1.0f);
                    v[r] = (__bf16)h1;
                }
                *(bf16x4*)&T[p * PITCH_H + lt * 16 + q * 4] = v;
            }
            ahb[2 * h]     = *(const bf16x8*)&T[p * PITCH_H + q * 8];
            ahb[2 * h + 1] = *(const bf16x8*)&T[p * PITCH_H + 32 + q * 8];
        }

        if (it == 0) {
            // prefetch z for it 1: latency hides under GEMM1+GEMM2
            if (q == 0) {
                const int sb1i = blockIdx.x * 256 + 128 + w * 32;
                const float4* zp0 = (const float4*)(z + (size_t)(sb1i + p) * 8);
                const float4* zp1 = (const float4*)(z + (size_t)(sb1i + 16 + p) * 8);
                zn0a = zp0[0]; zn1a = zp0[1]; zn0b = zp1[0]; zn1b = zp1[1];
            }
            // 2*b2 -> LDS, then the single barrier (drains staging DMA via vmcnt)
            if (tid < 128) sb2f[tid] = b2v;
            __syncthreads();
        }

        // ---- GEMM1: 2*h2pre = mfma(2W2^T-frag, h1^T-frag, C=2b2); shared W2 reads ----
        bf16x8 ah2a[4], ah2b[4];
        #pragma unroll
        for (int h = 0; h < 2; ++h) {
            floatx4 accA[4], accB[4];
            #pragma unroll
            for (int lt = 0; lt < 4; ++lt) {
                const int nt = 4 * h + lt;
                const floatx4 binit = *(const floatx4*)&sb2f[nt * 16 + q * 4]; // broadcast
                floatx4 a = binit, b = binit;
                #pragma unroll
                for (int kb = 0; kb < 4; ++kb) {
                    const bf16x8 wf = W2sv[(kb * 128 + nt * 16 + p) * 4 + q];
                    a = __builtin_amdgcn_mfma_f32_16x16x32_bf16(wf, aha[kb], a, 0, 0, 0);
                    b = __builtin_amdgcn_mfma_f32_16x16x32_bf16(wf, ahb[kb], b, 0, 0, 0);
                }
                accA[lt] = a; accB[lt] = b;
            }
            #pragma unroll
            for (int lt = 0; lt < 4; ++lt) {            // group a epilogue
                bf16x4 v;
                #pragma unroll
                for (int r = 0; r < 4; ++r) v[r] = (__bf16)fast_tanh2(accA[lt][r]);
                *(bf16x4*)&T[p * PITCH_H + lt * 16 + q * 4] = v;
            }
            ah2a[2 * h]     = *(const bf16x8*)&T[p * PITCH_H + q * 8];
            ah2a[2 * h + 1] = *(const bf16x8*)&T[p * PITCH_H + 32 + q * 8];
            #pragma unroll
            for (int lt = 0; lt < 4; ++lt) {            // group b epilogue
                bf16x4 v;
                #pragma unroll
                for (int r = 0; r < 4; ++r) v[r] = (__bf16)fast_tanh2(accB[lt][r]);
                *(bf16x4*)&T[p * PITCH_H + lt * 16 + q * 4] = v;
            }
            ah2b[2 * h]     = *(const bf16x8*)&T[p * PITCH_H + q * 8];
            ah2b[2 * h + 1] = *(const bf16x8*)&T[p * PITCH_H + 32 + q * 8];
        }

        // ---- GEMM3: dz^T = mfma(W3^T-frag, h2^T-frag, C=b3); float4 store ----
        floatx4 d3A = b3f, d3B = b3f;
        #pragma unroll
        for (int kb = 0; kb < 4; ++kb) {
            d3A = __builtin_amdgcn_mfma_f32_16x16x32_bf16(w3f[kb], ah2a[kb], d3A, 0, 0, 0);
            d3B = __builtin_amdgcn_mfma_f32_16x16x32_bf16(w3f[kb], ah2b[kb], d3B, 0, 0, 0);
        }
        if (q < 2) {
            *(floatx4*)(out + (size_t)(sbase + p) * 8 + q * 4) = d3A;
            *(floatx4*)(out + (size_t)(sbase + 16 + p) * 8 + q * 4) = d3B;
        }

        // a2 A-frags in-register: a2 = 1 - h2^2 (elementwise in k)
        bf16x8 aaA[4], aaB[4];
        #pragma unroll
        for (int kb = 0; kb < 4; ++kb) {
            #pragma unroll
            for (int j = 0; j < 8; ++j) {
                const float fa = (float)ah2a[kb][j];
                aaA[kb][j] = (__bf16)__builtin_fmaf(-fa, fa, 1.0f);
                const float fb = (float)ah2b[kb][j];
                aaB[kb][j] = (__bf16)__builtin_fmaf(-fb, fb, 1.0f);
            }
        }

        // ---- GEMM2: U^T = mfma(G-frag, a2^T-frag); trace scalar/lane ----
        float trA = 0.f, trB = 0.f;
        #pragma unroll
        for (int nt = 0; nt < 8; ++nt) {
            floatx4 uA = {0.f, 0.f, 0.f, 0.f}, uB = {0.f, 0.f, 0.f, 0.f};
            #pragma unroll
            for (int kb = 0; kb < 4; ++kb) {
                const bf16x8 gf = GTsv[(kb * 128 + nt * 16 + p) * 4 + q];
                uA = __builtin_amdgcn_mfma_f32_16x16x32_bf16(gf, aaA[kb], uA, 0, 0, 0);
                uB = __builtin_amdgcn_mfma_f32_16x16x32_bf16(gf, aaB[kb], uB, 0, 0, 0);
            }
            #pragma unroll
            for (int r = 0; r < 4; ++r) {
                trA = __builtin_fmaf(a1c0[nt * 4 + r], uA[r], trA);
                trB = __builtin_fmaf(a1c1[nt * 4 + r], uB[r], trB);
            }
        }
        trA += __shfl_xor(trA, 16, 64);
        trA += __shfl_xor(trA, 32, 64);
        trB += __shfl_xor(trB, 16, 64);
        trB += __shfl_xor(trB, 32, 64);
        if (lane < 16) {
            out[(size_t)BATCH * 8 + sbase + p] = -trA;
            out[(size_t)BATCH * 8 + sbase + 16 + p] = -trB;
        }

        // rotate prefetched z into current
        if (it == 0) { zc0a = zn0a; zc1a = zn1a; zc0b = zn0b; zc1b = zn1b; }
    }
}

extern "C" void kernel_launch(void* const* d_in, const int* in_sizes, int n_in,
                              void* d_out, int out_size, void* d_ws, size_t ws_size,
                              hipStream_t stream) {
    const float* z  = (const float*)d_in[0];
    // d_in[1] = logp_z (unused by the reference math)
    const float* t  = (const float*)d_in[2];
    const float* W1 = (const float*)d_in[3];
    const float* b1 = (const float*)d_in[4];
    const float* W2 = (const float*)d_in[5];
    const float* b2 = (const float*)d_in[6];
    const float* W3 = (const float*)d_in[7];
    const float* b3 = (const float*)d_in[8];
    __bf16* ws = (__bf16*)d_ws;
    float* out = (float*)d_out;

    prep_kernel<<<88, 256, 0, stream>>>(W1, W2, W3, b1, ws);
    cnf_main<<<512, 256, 0, stream>>>(z, t, b1, b2, b3, ws, out);
}